// Round 4
// baseline (540.447 us; speedup 1.0000x reference)
//
#include <hip/hip_runtime.h>
#include <hip/hip_fp16.h>

// Problem constants (fixed by the reference)
constexpr int NN    = 1024;  // tokens
constexpr int CZ    = 128;   // channels
constexpr int INDIM = 139;   // 4*32 + 2*2 + 7
// weight columns: [0,66) = pos, [66,132) = token, 132 = entity, [133,139) = chain

typedef float f4 __attribute__((ext_vector_type(4)));

// d_ws layout:
//   [0, 73728)        fp32 tables: P[66][128] | T[66][128] | C[2][6][128]
//   [73728, 77824)    packed attrs, one uint32 per token:
//                     asym[2:0] ent[4:3] sym[6:5] resi[16:7] tok[28:17]
constexpr int TBL_FLOATS = 18432;   // 8448 + 8448 + 1536
constexpr int TBL_BYTES  = TBL_FLOATS * 4;

// ---------------- kernel A: build tables + packed attrs (once) -------------
__global__ void build_tables(const int* __restrict__ asym, const int* __restrict__ resi,
                             const int* __restrict__ ent,  const int* __restrict__ tok,
                             const int* __restrict__ sym,  const float* __restrict__ w,
                             float* __restrict__ tbl, unsigned* __restrict__ packed)
{
    const int gtid   = blockIdx.x * 256 + threadIdx.x;
    const int stride = gridDim.x * 256;

    for (int idx = gtid; idx < 8448; idx += stride) {
        const int d = idx >> 7, c = idx & 127;
        tbl[idx]        = __half2float(__float2half(w[c * INDIM + d]));
        tbl[8448 + idx] = __half2float(__float2half(w[c * INDIM + 66 + d]));
    }
    for (int idx = gtid; idx < 768; idx += stride) {
        const int d = idx >> 7, c = idx & 127;
        const float ch = __half2float(__float2half(w[c * INDIM + 133 + d]));
        const float en = __half2float(__float2half(w[c * INDIM + 132]));
        tbl[16896 + idx]       = ch;        // same_ent == 0
        tbl[16896 + 768 + idx] = ch + en;   // same_ent == 1
    }
    for (int j = gtid; j < NN; j += stride) {
        packed[j] = (unsigned)(asym[j] & 7)
                  | ((unsigned)(ent[j]  & 3)    << 3)
                  | ((unsigned)(sym[j]  & 3)    << 5)
                  | ((unsigned)(resi[j] & 1023) << 7)
                  | ((unsigned)(tok[j]  & 4095) << 17);
    }
}

// ---------------- kernel B: main streaming kernel --------------------------
// grid = 512 blocks (2 per CU, all co-resident), block b handles
// i in {2b, 2b+1}, all 1024 j. Tables copied once per block.
__global__ __launch_bounds__(256, 2) void relpos_main(
    const float* __restrict__ tbl, const unsigned* __restrict__ packed,
    float* __restrict__ out)
{
    __shared__ __attribute__((aligned(16))) float    lds[TBL_FLOATS];
    __shared__ __attribute__((aligned(16))) unsigned attrs[NN];

    const int tid = threadIdx.x;

    // coalesced contiguous table copy: 4608 float4, 18 per thread
    {
        const f4* __restrict__ src = (const f4*)tbl;
        f4* __restrict__ dst = (f4*)lds;
        #pragma unroll
        for (int k = 0; k < 18; ++k) dst[tid + 256 * k] = src[tid + 256 * k];
    }
    #pragma unroll
    for (int k = 0; k < 4; ++k) attrs[tid + 256 * k] = packed[tid + 256 * k];
    __syncthreads();

    const int i0 = blockIdx.x << 1;

    const unsigned pi0 = packed[i0];       // tiny, L2-hot, wave-uniform
    const unsigned pi1 = packed[i0 + 1];
    const int a0 = pi0 & 7, e0 = (pi0 >> 3) & 3, s0 = (pi0 >> 5) & 3;
    const int r0 = (pi0 >> 7) & 1023, t0 = (pi0 >> 17) & 4095;
    const int a1 = pi1 & 7, e1 = (pi1 >> 3) & 3, s1 = (pi1 >> 5) & 3;
    const int r1 = (pi1 >> 7) & 1023, t1 = (pi1 >> 17) & 4095;

    const int g  = tid >> 5;          // pair-group 0..7 (8 j's per iteration)
    const int c4 = (tid & 31) << 2;   // channel base, float4 per lane

    float* outp0 = out + ((size_t)i0 << 17) + (size_t)g * CZ + c4;
    float* outp1 = outp0 + (1 << 17);

    #pragma unroll 4
    for (int jt = 0; jt < 128; ++jt) {
        const unsigned pj = attrs[jt * 8 + g];
        const int aj = pj & 7, ej = (pj >> 3) & 3, sj = (pj >> 5) & 3;
        const int rj = (pj >> 7) & 1023, tj = (pj >> 17) & 4095;

        // ---- row i0 ----
        {
            const bool sc = (a0 == aj);
            const bool sr = (r0 == rj);
            const int  se = (e0 == ej) ? 1 : 0;
            int dres = min(max(r0 - rj + 32, 0), 64);
            if (!sc) dres = 65;
            int dtok = min(max(t0 - tj + 32, 0), 64);
            if (!(sc && sr)) dtok = 65;
            int dch = min(max(s0 - sj + 2, 0), 4);
            if (!se) dch = 5;

            const f4 p  = *(const f4*)&lds[dres * 128 + c4];
            const f4 t  = *(const f4*)&lds[8448 + dtok * 128 + c4];
            const f4 cc = *(const f4*)&lds[16896 + se * 768 + dch * 128 + c4];
            __builtin_nontemporal_store(p + t + cc, (f4*)outp0);
        }
        // ---- row i1 ----
        {
            const bool sc = (a1 == aj);
            const bool sr = (r1 == rj);
            const int  se = (e1 == ej) ? 1 : 0;
            int dres = min(max(r1 - rj + 32, 0), 64);
            if (!sc) dres = 65;
            int dtok = min(max(t1 - tj + 32, 0), 64);
            if (!(sc && sr)) dtok = 65;
            int dch = min(max(s1 - sj + 2, 0), 4);
            if (!se) dch = 5;

            const f4 p  = *(const f4*)&lds[dres * 128 + c4];
            const f4 t  = *(const f4*)&lds[8448 + dtok * 128 + c4];
            const f4 cc = *(const f4*)&lds[16896 + se * 768 + dch * 128 + c4];
            __builtin_nontemporal_store(p + t + cc, (f4*)outp1);
        }
        outp0 += 8 * CZ;
        outp1 += 8 * CZ;
    }
}

extern "C" void kernel_launch(void* const* d_in, const int* in_sizes, int n_in,
                              void* d_out, int out_size, void* d_ws, size_t ws_size,
                              hipStream_t stream) {
    const int*   asym   = (const int*)d_in[0];
    const int*   resi   = (const int*)d_in[1];
    const int*   ent    = (const int*)d_in[2];
    const int*   tok    = (const int*)d_in[3];
    const int*   sym    = (const int*)d_in[4];
    const float* weight = (const float*)d_in[5];
    float*       out    = (float*)d_out;

    float*    tbl    = (float*)d_ws;
    unsigned* packed = (unsigned*)((char*)d_ws + TBL_BYTES);

    build_tables<<<16, 256, 0, stream>>>(asym, resi, ent, tok, sym, weight, tbl, packed);
    relpos_main<<<NN / 2, 256, 0, stream>>>(tbl, packed, out);
}

// Round 5
// 538.862 us; speedup vs baseline: 1.0029x; 1.0029x over previous
//
#include <hip/hip_runtime.h>
#include <hip/hip_fp16.h>

// Problem constants (fixed by the reference)
constexpr int NN    = 1024;  // tokens
constexpr int CZ    = 128;   // channels
constexpr int INDIM = 139;   // 4*32 + 2*2 + 7
constexpr int RAWW  = INDIM * CZ;  // 17792 raw weight floats
// weight columns: [0,66) = pos, [66,132) = token, 132 = entity, [133,139) = chain

typedef float f4 __attribute__((ext_vector_type(4)));

// LDS table layout (fp32, fp16-quantized values):
//   P[66][128] @ 0 | T[66][128] @ 8448 | C[2][6][128] @ 16896
// 18432 floats = 73728 B; raw weight (17792 floats) staged in the same
// buffer first, transposed into 72 regs/thread, then overwritten.
constexpr int TBL_FLOATS = 18432;
constexpr int KPT        = TBL_FLOATS / 256;  // 72 table entries per thread

__device__ __forceinline__ float q16(float x) {
    return __half2float(__float2half(x));  // fp16 RNE round-trip
}

// Single fused kernel. grid = 512 (2 blocks/CU, all co-resident); block b
// handles i in {2b, 2b+1}, all 1024 j.
__global__ __launch_bounds__(256, 2) void relpos_fused(
    const int* __restrict__ asym, const int* __restrict__ resi,
    const int* __restrict__ ent,  const int* __restrict__ tok,
    const int* __restrict__ sym,  const float* __restrict__ w,
    float* __restrict__ out)
{
    __shared__ __attribute__((aligned(16))) float    lds[TBL_FLOATS];
    __shared__ __attribute__((aligned(16))) unsigned attrs[NN];

    const int tid = threadIdx.x;

    // ---- phase 0: coalesced raw-weight load + attr pack ----
    for (int k = tid; k < RAWW; k += 256) lds[k] = w[k];
    #pragma unroll
    for (int k = 0; k < 4; ++k) {
        const int j = tid + 256 * k;
        attrs[j] = (unsigned)(asym[j] & 7)
                 | ((unsigned)(ent[j]  & 3)    << 3)
                 | ((unsigned)(sym[j]  & 3)    << 5)
                 | ((unsigned)(resi[j] & 1023) << 7)
                 | ((unsigned)(tok[j]  & 4095) << 17);
    }
    __syncthreads();

    // ---- phase 1: build 72 table entries in registers (static unroll;
    //      every k is a compile-time region: 33*256=8448, 66*256=16896) ----
    float r[KPT];
    #pragma unroll
    for (int k = 0; k < KPT; ++k) {
        const int idx = tid + 256 * k;
        if (k < 33) {                       // P[d][c] = q(w[c][d])
            const int d = idx >> 7, c = idx & 127;
            r[k] = q16(lds[c * INDIM + d]); // stride-139 lanes: bank-free
        } else if (k < 66) {                // T[d][c] = q(w[c][66+d])
            const int i2 = idx - 8448;
            const int d = i2 >> 7, c = i2 & 127;
            r[k] = q16(lds[c * INDIM + 66 + d]);
        } else {                            // C[se][d][c] = q(chain) + se*q(entity)
            const int i3  = idx - 16896;    // k 66..68 -> se=0, 69..71 -> se=1
            const int se  = (k >= 69) ? 1 : 0;
            const int rem = i3 - se * 768;
            const int d = rem >> 7, c = rem & 127;
            float v = q16(lds[c * INDIM + 133 + d]);
            if (se) v += q16(lds[c * INDIM + 132]);
            r[k] = v;
        }
    }
    __syncthreads();

    // ---- phase 2: overwrite LDS with tables (stride 256: bank-free) ----
    #pragma unroll
    for (int k = 0; k < KPT; ++k) lds[tid + 256 * k] = r[k];
    __syncthreads();

    // ---- phase 3: streaming main loop ----
    const int i0 = blockIdx.x << 1;
    const unsigned pi0 = attrs[i0];
    const unsigned pi1 = attrs[i0 + 1];
    const int a0 = pi0 & 7, e0 = (pi0 >> 3) & 3, s0 = (pi0 >> 5) & 3;
    const int r0 = (pi0 >> 7) & 1023, t0 = (pi0 >> 17) & 4095;
    const int a1 = pi1 & 7, e1 = (pi1 >> 3) & 3, s1 = (pi1 >> 5) & 3;
    const int r1 = (pi1 >> 7) & 1023, t1 = (pi1 >> 17) & 4095;

    const int g  = tid >> 5;          // pair-group 0..7 (8 j's per iteration)
    const int c4 = (tid & 31) << 2;   // channel base, float4 per lane

    float* outp0 = out + ((size_t)i0 << 17) + (size_t)g * CZ + c4;
    float* outp1 = outp0 + (1 << 17);

    #pragma unroll 4
    for (int jt = 0; jt < 128; ++jt) {
        const unsigned pj = attrs[jt * 8 + g];
        const int aj = pj & 7, ej = (pj >> 3) & 3, sj = (pj >> 5) & 3;
        const int rj = (pj >> 7) & 1023, tj = (pj >> 17) & 4095;

        // ---- row i0 ----
        {
            const bool sc = (a0 == aj);
            const bool sr = (r0 == rj);
            const int  se = (e0 == ej) ? 1 : 0;
            int dres = min(max(r0 - rj + 32, 0), 64);
            if (!sc) dres = 65;
            int dtok = min(max(t0 - tj + 32, 0), 64);
            if (!(sc && sr)) dtok = 65;
            int dch = min(max(s0 - sj + 2, 0), 4);
            if (!se) dch = 5;

            const f4 p  = *(const f4*)&lds[dres * 128 + c4];
            const f4 t  = *(const f4*)&lds[8448 + dtok * 128 + c4];
            const f4 cc = *(const f4*)&lds[16896 + se * 768 + dch * 128 + c4];
            __builtin_nontemporal_store(p + t + cc, (f4*)outp0);
        }
        // ---- row i1 ----
        {
            const bool sc = (a1 == aj);
            const bool sr = (r1 == rj);
            const int  se = (e1 == ej) ? 1 : 0;
            int dres = min(max(r1 - rj + 32, 0), 64);
            if (!sc) dres = 65;
            int dtok = min(max(t1 - tj + 32, 0), 64);
            if (!(sc && sr)) dtok = 65;
            int dch = min(max(s1 - sj + 2, 0), 4);
            if (!se) dch = 5;

            const f4 p  = *(const f4*)&lds[dres * 128 + c4];
            const f4 t  = *(const f4*)&lds[8448 + dtok * 128 + c4];
            const f4 cc = *(const f4*)&lds[16896 + se * 768 + dch * 128 + c4];
            __builtin_nontemporal_store(p + t + cc, (f4*)outp1);
        }
        outp0 += 8 * CZ;
        outp1 += 8 * CZ;
    }
}

extern "C" void kernel_launch(void* const* d_in, const int* in_sizes, int n_in,
                              void* d_out, int out_size, void* d_ws, size_t ws_size,
                              hipStream_t stream) {
    const int*   asym   = (const int*)d_in[0];
    const int*   resi   = (const int*)d_in[1];
    const int*   ent    = (const int*)d_in[2];
    const int*   tok    = (const int*)d_in[3];
    const int*   sym    = (const int*)d_in[4];
    const float* weight = (const float*)d_in[5];
    float*       out    = (float*)d_out;

    relpos_fused<<<NN / 2, 256, 0, stream>>>(asym, resi, ent, tok, sym, weight, out);
}